// Round 5
// baseline (1084.911 us; speedup 1.0000x reference)
//
#include <hip/hip_runtime.h>
#include <math.h>

#define E   1024
#define H   16
#define DH  64
#define CD  512
#define S   2048
#define B   16
#define SRC (S + 1)      // 2049
#define SPAD 2052        // padded score row stride
#define SCALE 0.125f     // DH^-0.5

// ws layout (float offsets)
#define OFF_CTXP 0                 // [B][E]
#define OFF_Q0   16384             // [B][E]
#define OFF_BKP  32768             // [E]
#define OFF_Q1S  33792             // [B][E]  (scaled q after ctx proj)
#define OFF_CK   50176             // [B][E]
#define OFF_TT   66560             // t_T [f=1024][bh=256]
#define OFF_C0   328704            // [bh]
#define OFF_GP   328960            // g_part [4][bh][E]; after k_gsum, [0] holds final g
#define OFF_SC2  591104            // score partials, e-half 1 [bh][SPAD] (reuses dead GP slab 1-2)
#define OFF_SC   1377536           // scores [bh][SPAD] (e-half 0 + c0; s=S from pre3b)
#define OFF_WT   1902848           // w_T [b][s=0..2048][h]
#define OFF_UP   2427392           // u_part [16][b][h][E]
#define OFF_U    6621696           // u [b][h][E]
#define OFF_AP   6883840           // attn_pre [b][E]

// ---------------- stage 1: ctxp, q0, bkp (16-lane-group GEMV) ----------------
__global__ __launch_bounds__(256) void k_pre1(
    const float* __restrict__ query, const float* __restrict__ context,
    const float* __restrict__ ipw, const float* __restrict__ ipb,
    const float* __restrict__ cw, const float* __restrict__ cb,
    float* __restrict__ ws)
{
    int b  = blockIdx.x >> 6;
    int et = blockIdx.x & 63;
    int grp = threadIdx.x >> 4, l = threadIdx.x & 15;
    int e = et * 16 + grp;
    const float* crow = cw + (size_t)e * (CD + E);
    const float* ctx  = context + b * CD;
    float a1 = 0.f;
    #pragma unroll
    for (int c = l * 4; c < CD; c += 64) {
        float4 w4 = *(const float4*)(crow + c);
        float4 x4 = *(const float4*)(ctx + c);
        a1 += w4.x*x4.x + w4.y*x4.y + w4.z*x4.z + w4.w*x4.w;
    }
    const float* qrow = query + b * E;
    const float* wrow = ipw + (size_t)e * E;   // Wq row e
    float a2 = 0.f;
    #pragma unroll
    for (int f = l * 4; f < E; f += 64) {
        float4 w4 = *(const float4*)(wrow + f);
        float4 x4 = *(const float4*)(qrow + f);
        a2 += w4.x*x4.x + w4.y*x4.y + w4.z*x4.z + w4.w*x4.w;
    }
    float a3 = 0.f;
    if (b == 0) {   // bkp[e] = Wc2[e,:]·ipb[E:2E]
        const float* c2 = crow + CD;
        const float* bk = ipb + E;
        #pragma unroll
        for (int f = l * 4; f < E; f += 64) {
            float4 w4 = *(const float4*)(c2 + f);
            float4 x4 = *(const float4*)(bk + f);
            a3 += w4.x*x4.x + w4.y*x4.y + w4.z*x4.z + w4.w*x4.w;
        }
    }
    #pragma unroll
    for (int m = 8; m >= 1; m >>= 1) {
        a1 += __shfl_xor(a1, m, 64);
        a2 += __shfl_xor(a2, m, 64);
        a3 += __shfl_xor(a3, m, 64);
    }
    if (l == 0) {
        ws[OFF_CTXP + b*E + e] = a1 + cb[e];
        ws[OFF_Q0   + b*E + e] = a2 + ipb[e];
        if (b == 0) ws[OFF_BKP + e] = a3;
    }
}

// ---------------- stage 2: q1s (scaled), ck ----------------
__global__ __launch_bounds__(256) void k_pre2(
    const float* __restrict__ cw, float* __restrict__ ws)
{
    int b  = blockIdx.x >> 6;
    int et = blockIdx.x & 63;
    int grp = threadIdx.x >> 4, l = threadIdx.x & 15;
    int e = et * 16 + grp;
    const float* q0 = ws + OFF_Q0 + b*E;
    const float* c2row = cw + (size_t)e * (CD + E) + CD;  // Wc2 row e
    float acc = 0.f;
    #pragma unroll
    for (int f = l * 4; f < E; f += 64) {
        float4 w4 = *(const float4*)(c2row + f);
        float4 x4 = *(const float4*)(q0 + f);
        acc += w4.x*x4.x + w4.y*x4.y + w4.z*x4.z + w4.w*x4.w;
    }
    #pragma unroll
    for (int m = 8; m >= 1; m >>= 1) acc += __shfl_xor(acc, m, 64);
    if (l == 0) {
        float ctxp = ws[OFF_CTXP + b*E + e];
        ws[OFF_Q1S + b*E + e] = (ctxp + acc) * SCALE;
        ws[OFF_CK  + b*E + e] = ctxp + ws[OFF_BKP + e];
    }
}

// ---------------- stage 3: t_T[f][bh] ----------------
__global__ __launch_bounds__(256) void k_pre3(
    const float* __restrict__ cw, float* __restrict__ ws)
{
    int bh = blockIdx.x >> 2;
    int f  = ((blockIdx.x & 3) << 8) + threadIdx.x;
    int b = bh >> 4, h = bh & 15;
    const float* q1 = ws + OFF_Q1S + b*E + h*DH;
    float acc = 0.f;
    #pragma unroll 8
    for (int d = 0; d < DH; ++d)
        acc += q1[d] * cw[(size_t)(h*DH + d)*(CD+E) + CD + f];
    ws[OFF_TT + f*256 + bh] = acc;
}

// ---------------- stage 3b: c0[bh], score at s=S ----------------
__global__ __launch_bounds__(256) void k_pre3b(
    const float* __restrict__ bias_k, float* __restrict__ ws)
{
    int bh = threadIdx.x;        // 1 block of 256
    int b = bh >> 4, h = bh & 15;
    const float* q1 = ws + OFF_Q1S + b*E + h*DH;
    const float* ck = ws + OFF_CK  + b*E + h*DH;
    const float* bk = bias_k + h*DH;
    float c0 = 0.f, sb = 0.f;
    for (int d = 0; d < DH; ++d) { float q = q1[d]; c0 += q*ck[d]; sb += q*bk[d]; }
    ws[OFF_C0 + bh] = c0;
    ws[OFF_SC + (size_t)bh*SPAD + S] = sb;   // bias_k position score
}

// ---------------- g_part[kc][bh][e] (m-tile of 8, 512 blocks = 2/CU) -------
__global__ __launch_bounds__(256) void k_g(
    const float* __restrict__ ipw, float* __restrict__ ws)
{
    int kc = blockIdx.x >> 7;            // 0..3  (f chunk of 256)
    int nt = (blockIdx.x >> 5) & 3;      // n tile of 256
    int mt = blockIdx.x & 31;            // m tile of 8 (bh)
    int n  = (nt << 8) + threadIdx.x;
    int m0 = mt << 3;
    int f0 = kc << 8;
    const float* tT = ws + OFF_TT;
    const float* wk = ipw + (size_t)E * E;   // Wk rows
    float acc[8];
    #pragma unroll
    for (int m = 0; m < 8; ++m) acc[m] = 0.f;
    #pragma unroll 4
    for (int f = f0; f < f0 + 256; ++f) {
        float wv = wk[(size_t)f*E + n];
        const float* tr = tT + f*256 + m0;   // uniform -> scalar loads
        #pragma unroll
        for (int m = 0; m < 8; ++m) acc[m] += tr[m] * wv;
    }
    float* gp = ws + OFF_GP + (size_t)kc * (256*E);
    #pragma unroll
    for (int m = 0; m < 8; ++m) gp[(size_t)(m0+m)*E + n] = acc[m];
}

// ---------------- sum 4 g partials into slab 0 ----------------
__global__ __launch_bounds__(256) void k_gsum(float* __restrict__ ws)
{
    int id = blockIdx.x * 256 + threadIdx.x;   // 262144 threads
    float a = ws[OFF_GP + id]
            + ws[OFF_GP + 1*(256*E) + id]
            + ws[OFF_GP + 2*(256*E) + id]
            + ws[OFF_GP + 3*(256*E) + id];
    ws[OFF_GP + id] = a;
}

// ---------------- scores: partial over e-half, 2 rows/thread ---------------
// 512 thr / 8 waves; wave = e-chunk of 64 within this block's e-half;
// lane = s-row; thread owns rows (r0, r0+64) -> g LDS broadcasts amortized
// over 2 rows (256 ds_read_b128 per 4096 FMA). Cross-wave e-reduce via
// 17-stride LDS partials, 2 phases reusing the g buffer. eh=0 adds c0 ->
// OFF_SC; eh=1 raw -> OFF_SC2 (summed in k_softmax).
__global__ __launch_bounds__(512) void k_scores(
    const float* __restrict__ key, float* __restrict__ ws)
{
    __shared__ float lds[8704];    // 34 KB: phase1 g[16][512]; phase2 [512][17]
    int eh = blockIdx.x & 1;
    int sc = (blockIdx.x >> 1) & 15;
    int b  = blockIdx.x >> 5;
    const float* gsrc = ws + OFF_GP + (size_t)b*(16*1024) + eh*512;
    for (int i = threadIdx.x; i < 2048; i += 512) {
        int h = i >> 7, c = i & 127;
        ((float4*)lds)[i] = *(const float4*)(gsrc + (size_t)h*1024 + c*4);
    }
    __syncthreads();

    int w = threadIdx.x >> 6, l = threadIdx.x & 63;
    int r0 = sc*128 + l;                 // rows r0 and r0+64
    const float* kr0 = key + (((size_t)(r0*B + b)) << 10) + eh*512 + w*64;
    const float* kr1 = kr0 + ((size_t)(64*B) << 10);
    float acc0[16], acc1[16];
    #pragma unroll
    for (int h = 0; h < 16; ++h) { acc0[h] = 0.f; acc1[h] = 0.f; }

    const float4* g4 = (const float4*)lds;
    #pragma unroll
    for (int win = 0; win < 4; ++win) {
        const float* kp0 = kr0 + win*16;
        const float* kp1 = kr1 + win*16;
        float4 a0 = *(const float4*)(kp0);
        float4 a1 = *(const float4*)(kp0 + 4);
        float4 a2 = *(const float4*)(kp0 + 8);
        float4 a3 = *(const float4*)(kp0 + 12);
        float4 b0 = *(const float4*)(kp1);
        float4 b1 = *(const float4*)(kp1 + 4);
        float4 b2 = *(const float4*)(kp1 + 8);
        float4 b3 = *(const float4*)(kp1 + 12);
        int gb = w*16 + win*4;           // float4 index within [128] per h
        #pragma unroll
        for (int h = 0; h < 16; ++h) {
            float4 g0 = g4[h*128 + gb];
            float4 g1 = g4[h*128 + gb + 1];
            float4 g2 = g4[h*128 + gb + 2];
            float4 g3 = g4[h*128 + gb + 3];
            acc0[h] += a0.x*g0.x + a0.y*g0.y + a0.z*g0.z + a0.w*g0.w
                     + a1.x*g1.x + a1.y*g1.y + a1.z*g1.z + a1.w*g1.w
                     + a2.x*g2.x + a2.y*g2.y + a2.z*g2.z + a2.w*g2.w
                     + a3.x*g3.x + a3.y*g3.y + a3.z*g3.z + a3.w*g3.w;
            acc1[h] += b0.x*g0.x + b0.y*g0.y + b0.z*g0.z + b0.w*g0.w
                     + b1.x*g1.x + b1.y*g1.y + b1.z*g1.z + b1.w*g1.w
                     + b2.x*g2.x + b2.y*g2.y + b2.z*g2.z + b2.w*g2.w
                     + b3.x*g3.x + b3.y*g3.y + b3.z*g3.z + b3.w*g3.w;
        }
    }
    __syncthreads();   // done reading g; reuse LDS for partials

    float* pr = lds + threadIdx.x*17;
    int l2 = threadIdx.x & 63, pp = threadIdx.x >> 6;
    // phase A: rows sc*128 + l2
    #pragma unroll
    for (int h = 0; h < 16; ++h) pr[h] = acc0[h];
    __syncthreads();
    #pragma unroll
    for (int k2 = 0; k2 < 2; ++k2) {
        int h = pp*2 + k2;
        float sum = 0.f;
        #pragma unroll
        for (int ww = 0; ww < 8; ++ww) sum += lds[(ww*64 + l2)*17 + h];
        int bh = b*16 + h;
        int s  = sc*128 + l2;
        if (eh == 0) ws[OFF_SC  + (size_t)bh*SPAD + s] = sum + ws[OFF_C0 + bh];
        else         ws[OFF_SC2 + (size_t)bh*SPAD + s] = sum;
    }
    __syncthreads();
    // phase B: rows sc*128 + 64 + l2
    #pragma unroll
    for (int h = 0; h < 16; ++h) pr[h] = acc1[h];
    __syncthreads();
    #pragma unroll
    for (int k2 = 0; k2 < 2; ++k2) {
        int h = pp*2 + k2;
        float sum = 0.f;
        #pragma unroll
        for (int ww = 0; ww < 8; ++ww) sum += lds[(ww*64 + l2)*17 + h];
        int bh = b*16 + h;
        int s  = sc*128 + 64 + l2;
        if (eh == 0) ws[OFF_SC  + (size_t)bh*SPAD + s] = sum + ws[OFF_C0 + bh];
        else         ws[OFF_SC2 + (size_t)bh*SPAD + s] = sum;
    }
}

// ---------------- softmax per (b,h) row; write w_T[b][s][h] ----------------
__global__ __launch_bounds__(256) void k_softmax(float* __restrict__ ws)
{
    int bh = blockIdx.x; int b = bh >> 4, h = bh & 15;
    int tid = threadIdx.x, lane = tid & 63, wid = tid >> 6;
    const float* row  = ws + OFF_SC  + (size_t)bh*SPAD;
    const float* row2 = ws + OFF_SC2 + (size_t)bh*SPAD;
    __shared__ float red[4];
    float v[9];
    float m = -1e30f;
    #pragma unroll
    for (int i = 0; i < 9; ++i) {
        int s = tid + (i << 8);
        if (s < SRC) {
            v[i] = row[s] + (s < S ? row2[s] : 0.f);
            m = fmaxf(m, v[i]);
        } else v[i] = -1e30f;
    }
    #pragma unroll
    for (int k = 1; k < 64; k <<= 1) m = fmaxf(m, __shfl_xor(m, k, 64));
    if (lane == 0) red[wid] = m;
    __syncthreads();
    m = fmaxf(fmaxf(red[0], red[1]), fmaxf(red[2], red[3]));
    __syncthreads();
    float sum = 0.f;
    #pragma unroll
    for (int i = 0; i < 9; ++i) {
        int s = tid + (i << 8);
        if (s < SRC) { v[i] = expf(v[i] - m); sum += v[i]; }
    }
    #pragma unroll
    for (int k = 1; k < 64; k <<= 1) sum += __shfl_xor(sum, k, 64);
    if (lane == 0) red[wid] = sum;
    __syncthreads();
    sum = red[0] + red[1] + red[2] + red[3];
    float inv = 1.0f / sum;
    float* wt = ws + OFF_WT;
    #pragma unroll
    for (int i = 0; i < 9; ++i) {
        int s = tid + (i << 8);
        if (s < SRC) wt[((size_t)(b*SRC + s) << 4) + h] = v[i] * inv;
    }
}

// ---------------- avg_weights output ----------------
__global__ __launch_bounds__(256) void k_avg(
    const float* __restrict__ ws, float* __restrict__ out)
{
    int id = blockIdx.x * 256 + threadIdx.x;
    if (id >= B * SRC) return;
    const float* p = ws + OFF_WT + (size_t)id * 16;
    float a = 0.f;
    #pragma unroll
    for (int j = 0; j < 16; j += 4) {
        float4 w4 = *(const float4*)(p + j);
        a += w4.x + w4.y + w4.z + w4.w;
    }
    out[B*E + id] = a * (1.0f / H);
}

// ---------------- u_part[sc][b][h][f] = Σ_s w·value ----------------
__global__ __launch_bounds__(256) void k_u(
    const float* __restrict__ value, float* __restrict__ ws)
{
    int b  = blockIdx.x >> 5;
    int sc = (blockIdx.x >> 1) & 15;     // 16 s-chunks of 128
    int fh = blockIdx.x & 1;             // f half
    int f  = (fh << 9) + threadIdx.x * 2;
    float2 acc[16];
    #pragma unroll
    for (int h = 0; h < 16; ++h) { acc[h].x = 0.f; acc[h].y = 0.f; }
    int s0 = sc << 7;
    for (int i = 0; i < 128; ++i) {
        int s = s0 + i;
        const float* wr = ws + OFF_WT + ((size_t)(b*SRC + s) << 4); // uniform
        float2 vv = *(const float2*)(value + (((size_t)s*B + b) << 10) + f);
        #pragma unroll
        for (int h = 0; h < 16; ++h) {
            float wv = wr[h];
            acc[h].x += wv * vv.x; acc[h].y += wv * vv.y;
        }
    }
    float* up = ws + OFF_UP + ((size_t)(sc*B + b) << 4) * E;
    #pragma unroll
    for (int h = 0; h < 16; ++h)
        *(float2*)(up + (size_t)h*E + f) = acc[h];
}

// ---------------- reduce u_part ----------------
__global__ __launch_bounds__(256) void k_ured(float* __restrict__ ws)
{
    int id = blockIdx.x * 256 + threadIdx.x;   // 262144 threads
    float a = 0.f;
    #pragma unroll
    for (int c = 0; c < 16; ++c) a += ws[OFF_UP + (size_t)c*(B*H*E) + id];
    ws[OFF_U + id] = a;
}

// ---------------- attn_pre[b][e] (16-lane-group GEMV) ----------------
__global__ __launch_bounds__(256) void k_attnpre(
    const float* __restrict__ ipw, const float* __restrict__ ipb,
    const float* __restrict__ bias_v, float* __restrict__ ws)
{
    int b  = blockIdx.x >> 6;
    int et = blockIdx.x & 63;
    int grp = threadIdx.x >> 4, l = threadIdx.x & 15;
    int e = et * 16 + grp;
    int h = e >> 6;
    const float* wvr = ipw + (size_t)(2*E + e) * E;   // Wv row e
    const float* ur  = ws + OFF_U + (size_t)(b*16 + h) * E;
    float acc = 0.f;
    #pragma unroll
    for (int ff = l * 4; ff < E; ff += 64) {
        float4 w4 = *(const float4*)(wvr + ff);
        float4 u4 = *(const float4*)(ur + ff);
        acc += w4.x*u4.x + w4.y*u4.y + w4.z*u4.z + w4.w*u4.w;
    }
    #pragma unroll
    for (int m = 8; m >= 1; m >>= 1) acc += __shfl_xor(acc, m, 64);
    if (l == 0) {
        float wS = ws[OFF_WT + ((size_t)(b*SRC + S) << 4) + h];
        ws[OFF_AP + b*E + e] = acc + ipb[2*E + e] * (1.0f - wS) + wS * bias_v[e];
    }
}

// ---------------- out projection (16-lane-group GEMV) ----------------
__global__ __launch_bounds__(256) void k_out(
    const float* __restrict__ ow, const float* __restrict__ ob,
    const float* __restrict__ ws, float* __restrict__ out)
{
    int b  = blockIdx.x >> 6;
    int et = blockIdx.x & 63;
    int grp = threadIdx.x >> 4, l = threadIdx.x & 15;
    int o = et * 16 + grp;
    const float* wr = ow + (size_t)o * E;
    const float* ap = ws + OFF_AP + b*E;
    float acc = 0.f;
    #pragma unroll
    for (int e = l * 4; e < E; e += 64) {
        float4 w4 = *(const float4*)(wr + e);
        float4 a4 = *(const float4*)(ap + e);
        acc += w4.x*a4.x + w4.y*a4.y + w4.z*a4.z + w4.w*a4.w;
    }
    #pragma unroll
    for (int m = 8; m >= 1; m >>= 1) acc += __shfl_xor(acc, m, 64);
    if (l == 0) out[b*E + o] = acc + ob[o];
}

extern "C" void kernel_launch(void* const* d_in, const int* in_sizes, int n_in,
                              void* d_out, int out_size, void* d_ws, size_t ws_size,
                              hipStream_t stream)
{
    const float* query   = (const float*)d_in[0];
    const float* key     = (const float*)d_in[1];
    const float* value   = (const float*)d_in[2];
    const float* context = (const float*)d_in[3];
    const float* ipw     = (const float*)d_in[4];
    const float* ipb     = (const float*)d_in[5];
    const float* cw      = (const float*)d_in[6];
    const float* cb      = (const float*)d_in[7];
    const float* ow      = (const float*)d_in[8];
    const float* ob      = (const float*)d_in[9];
    const float* bias_k  = (const float*)d_in[10];
    const float* bias_v  = (const float*)d_in[11];
    float* out = (float*)d_out;
    float* ws  = (float*)d_ws;

    hipLaunchKernelGGL(k_pre1,    dim3(1024), dim3(256),  0, stream, query, context, ipw, ipb, cw, cb, ws);
    hipLaunchKernelGGL(k_pre2,    dim3(1024), dim3(256),  0, stream, cw, ws);
    hipLaunchKernelGGL(k_pre3,    dim3(1024), dim3(256),  0, stream, cw, ws);
    hipLaunchKernelGGL(k_pre3b,   dim3(1),    dim3(256),  0, stream, bias_k, ws);
    hipLaunchKernelGGL(k_g,       dim3(512),  dim3(256),  0, stream, ipw, ws);
    hipLaunchKernelGGL(k_gsum,    dim3(1024), dim3(256),  0, stream, ws);
    hipLaunchKernelGGL(k_scores,  dim3(512),  dim3(512),  0, stream, key, ws);
    hipLaunchKernelGGL(k_softmax, dim3(256),  dim3(256),  0, stream, ws);
    hipLaunchKernelGGL(k_avg,     dim3(129),  dim3(256),  0, stream, ws, out);
    hipLaunchKernelGGL(k_u,       dim3(512),  dim3(256),  0, stream, value, ws);
    hipLaunchKernelGGL(k_ured,    dim3(1024), dim3(256),  0, stream, ws);
    hipLaunchKernelGGL(k_attnpre, dim3(1024), dim3(256),  0, stream, ipw, ipb, bias_v, ws);
    hipLaunchKernelGGL(k_out,     dim3(1024), dim3(256),  0, stream, ow, ob, ws, out);
}

// Round 6
// 193.258 us; speedup vs baseline: 5.6138x; 5.6138x over previous
//
#include <hip/hip_runtime.h>
#include <math.h>

#define E   1024
#define H   16
#define DH  64
#define CD  512
#define S   2048
#define B   16
#define SRC (S + 1)      // 2049
#define SPAD 2052        // padded score row stride
#define SCALE 0.125f     // DH^-0.5

// ws layout (float offsets)
#define OFF_CTXP 0                 // [B][E]
#define OFF_Q0   16384             // [B][E]
#define OFF_BKP  32768             // [E]
#define OFF_Q1S  33792             // [B][E]  (scaled q after ctx proj)
#define OFF_CK   50176             // [B][E]
#define OFF_TT   66560             // t_T [f=1024][bh=256]
#define OFF_C0   328704            // [bh]
#define OFF_GP   328960            // g_part [4][bh][E]; after k_gsum, [0] holds final g
#define OFF_SC   1377536           // scores [bh][SPAD] (s=S slot from pre3b)
#define OFF_WT   1902848           // w_T [b][s=0..2048][h]
#define OFF_UP   2427392           // u_part [16][b][h][E]
#define OFF_U    6621696           // u [b][h][E]
#define OFF_AP   6883840           // attn_pre [b][E]

// ---------------- stage 1: ctxp, q0, bkp (16-lane-group GEMV) ----------------
__global__ __launch_bounds__(256) void k_pre1(
    const float* __restrict__ query, const float* __restrict__ context,
    const float* __restrict__ ipw, const float* __restrict__ ipb,
    const float* __restrict__ cw, const float* __restrict__ cb,
    float* __restrict__ ws)
{
    int b  = blockIdx.x >> 6;
    int et = blockIdx.x & 63;
    int grp = threadIdx.x >> 4, l = threadIdx.x & 15;
    int e = et * 16 + grp;
    const float* crow = cw + (size_t)e * (CD + E);
    const float* ctx  = context + b * CD;
    float a1 = 0.f;
    #pragma unroll
    for (int c = l * 4; c < CD; c += 64) {
        float4 w4 = *(const float4*)(crow + c);
        float4 x4 = *(const float4*)(ctx + c);
        a1 += w4.x*x4.x + w4.y*x4.y + w4.z*x4.z + w4.w*x4.w;
    }
    const float* qrow = query + b * E;
    const float* wrow = ipw + (size_t)e * E;   // Wq row e
    float a2 = 0.f;
    #pragma unroll
    for (int f = l * 4; f < E; f += 64) {
        float4 w4 = *(const float4*)(wrow + f);
        float4 x4 = *(const float4*)(qrow + f);
        a2 += w4.x*x4.x + w4.y*x4.y + w4.z*x4.z + w4.w*x4.w;
    }
    float a3 = 0.f;
    if (b == 0) {   // bkp[e] = Wc2[e,:]·ipb[E:2E]
        const float* c2 = crow + CD;
        const float* bk = ipb + E;
        #pragma unroll
        for (int f = l * 4; f < E; f += 64) {
            float4 w4 = *(const float4*)(c2 + f);
            float4 x4 = *(const float4*)(bk + f);
            a3 += w4.x*x4.x + w4.y*x4.y + w4.z*x4.z + w4.w*x4.w;
        }
    }
    #pragma unroll
    for (int m = 8; m >= 1; m >>= 1) {
        a1 += __shfl_xor(a1, m, 64);
        a2 += __shfl_xor(a2, m, 64);
        a3 += __shfl_xor(a3, m, 64);
    }
    if (l == 0) {
        ws[OFF_CTXP + b*E + e] = a1 + cb[e];
        ws[OFF_Q0   + b*E + e] = a2 + ipb[e];
        if (b == 0) ws[OFF_BKP + e] = a3;
    }
}

// ---------------- stage 2: q1s (scaled), ck ----------------
__global__ __launch_bounds__(256) void k_pre2(
    const float* __restrict__ cw, float* __restrict__ ws)
{
    int b  = blockIdx.x >> 6;
    int et = blockIdx.x & 63;
    int grp = threadIdx.x >> 4, l = threadIdx.x & 15;
    int e = et * 16 + grp;
    const float* q0 = ws + OFF_Q0 + b*E;
    const float* c2row = cw + (size_t)e * (CD + E) + CD;  // Wc2 row e
    float acc = 0.f;
    #pragma unroll
    for (int f = l * 4; f < E; f += 64) {
        float4 w4 = *(const float4*)(c2row + f);
        float4 x4 = *(const float4*)(q0 + f);
        acc += w4.x*x4.x + w4.y*x4.y + w4.z*x4.z + w4.w*x4.w;
    }
    #pragma unroll
    for (int m = 8; m >= 1; m >>= 1) acc += __shfl_xor(acc, m, 64);
    if (l == 0) {
        float ctxp = ws[OFF_CTXP + b*E + e];
        ws[OFF_Q1S + b*E + e] = (ctxp + acc) * SCALE;
        ws[OFF_CK  + b*E + e] = ctxp + ws[OFF_BKP + e];
    }
}

// ---------------- stage 3: t_T[f][bh] ----------------
__global__ __launch_bounds__(256) void k_pre3(
    const float* __restrict__ cw, float* __restrict__ ws)
{
    int bh = blockIdx.x >> 2;
    int f  = ((blockIdx.x & 3) << 8) + threadIdx.x;
    int b = bh >> 4, h = bh & 15;
    const float* q1 = ws + OFF_Q1S + b*E + h*DH;
    float acc = 0.f;
    #pragma unroll 8
    for (int d = 0; d < DH; ++d)
        acc += q1[d] * cw[(size_t)(h*DH + d)*(CD+E) + CD + f];
    ws[OFF_TT + f*256 + bh] = acc;
}

// ---------------- stage 3b: c0[bh], score at s=S ----------------
__global__ __launch_bounds__(256) void k_pre3b(
    const float* __restrict__ bias_k, float* __restrict__ ws)
{
    int bh = threadIdx.x;        // 1 block of 256
    int b = bh >> 4, h = bh & 15;
    const float* q1 = ws + OFF_Q1S + b*E + h*DH;
    const float* ck = ws + OFF_CK  + b*E + h*DH;
    const float* bk = bias_k + h*DH;
    float c0 = 0.f, sb = 0.f;
    for (int d = 0; d < DH; ++d) { float q = q1[d]; c0 += q*ck[d]; sb += q*bk[d]; }
    ws[OFF_C0 + bh] = c0;
    ws[OFF_SC + (size_t)bh*SPAD + S] = sb;   // bias_k position score
}

// ---------------- g_part[kc][bh][e] (m-tile of 8, 512 blocks = 2/CU) -------
__global__ __launch_bounds__(256) void k_g(
    const float* __restrict__ ipw, float* __restrict__ ws)
{
    int kc = blockIdx.x >> 7;            // 0..3  (f chunk of 256)
    int nt = (blockIdx.x >> 5) & 3;      // n tile of 256
    int mt = blockIdx.x & 31;            // m tile of 8 (bh)
    int n  = (nt << 8) + threadIdx.x;
    int m0 = mt << 3;
    int f0 = kc << 8;
    const float* tT = ws + OFF_TT;
    const float* wk = ipw + (size_t)E * E;   // Wk rows
    float acc[8];
    #pragma unroll
    for (int m = 0; m < 8; ++m) acc[m] = 0.f;
    #pragma unroll 4
    for (int f = f0; f < f0 + 256; ++f) {
        float wv = wk[(size_t)f*E + n];
        const float* tr = tT + f*256 + m0;   // uniform -> scalar loads
        #pragma unroll
        for (int m = 0; m < 8; ++m) acc[m] += tr[m] * wv;
    }
    float* gp = ws + OFF_GP + (size_t)kc * (256*E);
    #pragma unroll
    for (int m = 0; m < 8; ++m) gp[(size_t)(m0+m)*E + n] = acc[m];
}

// ---------------- sum 4 g partials into slab 0 ----------------
__global__ __launch_bounds__(256) void k_gsum(float* __restrict__ ws)
{
    int id = blockIdx.x * 256 + threadIdx.x;   // 262144 threads
    float a = ws[OFF_GP + id]
            + ws[OFF_GP + 1*(256*E) + id]
            + ws[OFF_GP + 2*(256*E) + id]
            + ws[OFF_GP + 3*(256*E) + id];
    ws[OFF_GP + id] = a;
}

// ---------------- scores[bh][s] = key·g + c0 (scalar-g GEMV) ---------------
// lane = s-row, wave = e-chunk of 128. g addresses are SGPR-uniform (wave id
// via readfirstlane) -> scalar s_load operands; key staged 8 float4 at a time
// in VGPRs (#pragma unroll 1 keeps live set ~90 regs). No LDS in inner loop;
// LDS only for the 8-wave e-reduction (17-stride, conflict-free).
__global__ __launch_bounds__(512, 2) void k_scores(
    const float* __restrict__ key, float* __restrict__ ws)
{
    __shared__ float lds[8704];    // [8][64][17] = 34.8 KB
    int b  = blockIdx.x >> 5;
    int sc = blockIdx.x & 31;      // s-chunk of 64 rows
    int tid = threadIdx.x;
    int w = __builtin_amdgcn_readfirstlane(tid >> 6);   // wave id 0..7 (SGPR)
    int l = tid & 63;
    int r = sc*64 + l;
    const float* kbase = key + (((size_t)r*B + b) << 10) + w*128;
    const float* gbase = ws + OFF_GP + (size_t)b*(16*1024) + w*128;  // uniform
    float acc[16];
    #pragma unroll
    for (int h = 0; h < 16; ++h) acc[h] = 0.f;

    #pragma unroll 1
    for (int sub = 0; sub < 4; ++sub) {
        const float* kp = kbase + sub*32;
        float4 kk[8];
        #pragma unroll
        for (int j = 0; j < 8; ++j) kk[j] = *(const float4*)(kp + j*4);
        const float* gp0 = gbase + sub*32;
        #pragma unroll
        for (int h = 0; h < 16; ++h) {
            const float* gp = gp0 + h*1024;      // uniform -> s_load
            float a = 0.f;
            #pragma unroll
            for (int j = 0; j < 8; ++j) {
                float4 gv = *(const float4*)(gp + j*4);
                a += kk[j].x*gv.x + kk[j].y*gv.y + kk[j].z*gv.z + kk[j].w*gv.w;
            }
            acc[h] += a;
        }
    }

    float* pr = lds + (w*64 + l)*17;
    #pragma unroll
    for (int h = 0; h < 16; ++h) pr[h] = acc[h];
    __syncthreads();

    int l2 = tid & 63, pp = tid >> 6;
    #pragma unroll
    for (int k2 = 0; k2 < 2; ++k2) {
        int h = pp*2 + k2;
        float sum = 0.f;
        #pragma unroll
        for (int ww = 0; ww < 8; ++ww) sum += lds[(ww*64 + l2)*17 + h];
        int bh = b*16 + h;
        ws[OFF_SC + (size_t)bh*SPAD + sc*64 + l2] = sum + ws[OFF_C0 + bh];
    }
}

// ---------------- softmax per (b,h) row; write w_T[b][s][h] ----------------
__global__ __launch_bounds__(256) void k_softmax(float* __restrict__ ws)
{
    int bh = blockIdx.x; int b = bh >> 4, h = bh & 15;
    int tid = threadIdx.x, lane = tid & 63, wid = tid >> 6;
    const float* row = ws + OFF_SC + (size_t)bh*SPAD;
    __shared__ float red[4];
    float v[9];
    float m = -1e30f;
    #pragma unroll
    for (int i = 0; i < 9; ++i) {
        int s = tid + (i << 8);
        if (s < SRC) { v[i] = row[s]; m = fmaxf(m, v[i]); } else v[i] = -1e30f;
    }
    #pragma unroll
    for (int k = 1; k < 64; k <<= 1) m = fmaxf(m, __shfl_xor(m, k, 64));
    if (lane == 0) red[wid] = m;
    __syncthreads();
    m = fmaxf(fmaxf(red[0], red[1]), fmaxf(red[2], red[3]));
    __syncthreads();
    float sum = 0.f;
    #pragma unroll
    for (int i = 0; i < 9; ++i) {
        int s = tid + (i << 8);
        if (s < SRC) { v[i] = expf(v[i] - m); sum += v[i]; }
    }
    #pragma unroll
    for (int k = 1; k < 64; k <<= 1) sum += __shfl_xor(sum, k, 64);
    if (lane == 0) red[wid] = sum;
    __syncthreads();
    sum = red[0] + red[1] + red[2] + red[3];
    float inv = 1.0f / sum;
    float* wt = ws + OFF_WT;
    #pragma unroll
    for (int i = 0; i < 9; ++i) {
        int s = tid + (i << 8);
        if (s < SRC) wt[((size_t)(b*SRC + s) << 4) + h] = v[i] * inv;
    }
}

// ---------------- avg_weights output ----------------
__global__ __launch_bounds__(256) void k_avg(
    const float* __restrict__ ws, float* __restrict__ out)
{
    int id = blockIdx.x * 256 + threadIdx.x;
    if (id >= B * SRC) return;
    const float* p = ws + OFF_WT + (size_t)id * 16;
    float a = 0.f;
    #pragma unroll
    for (int j = 0; j < 16; j += 4) {
        float4 w4 = *(const float4*)(p + j);
        a += w4.x + w4.y + w4.z + w4.w;
    }
    out[B*E + id] = a * (1.0f / H);
}

// ---------------- u_part[sc][b][h][f] = Σ_s w·value ----------------
__global__ __launch_bounds__(256) void k_u(
    const float* __restrict__ value, float* __restrict__ ws)
{
    int b  = blockIdx.x >> 5;
    int sc = (blockIdx.x >> 1) & 15;     // 16 s-chunks of 128
    int fh = blockIdx.x & 1;             // f half
    int f  = (fh << 9) + threadIdx.x * 2;
    float2 acc[16];
    #pragma unroll
    for (int h = 0; h < 16; ++h) { acc[h].x = 0.f; acc[h].y = 0.f; }
    int s0 = sc << 7;
    for (int i = 0; i < 128; ++i) {
        int s = s0 + i;
        const float* wr = ws + OFF_WT + ((size_t)(b*SRC + s) << 4); // uniform
        float2 vv = *(const float2*)(value + (((size_t)s*B + b) << 10) + f);
        #pragma unroll
        for (int h = 0; h < 16; ++h) {
            float wv = wr[h];
            acc[h].x += wv * vv.x; acc[h].y += wv * vv.y;
        }
    }
    float* up = ws + OFF_UP + ((size_t)(sc*B + b) << 4) * E;
    #pragma unroll
    for (int h = 0; h < 16; ++h)
        *(float2*)(up + (size_t)h*E + f) = acc[h];
}

// ---------------- reduce u_part ----------------
__global__ __launch_bounds__(256) void k_ured(float* __restrict__ ws)
{
    int id = blockIdx.x * 256 + threadIdx.x;   // 262144 threads
    float a = 0.f;
    #pragma unroll
    for (int c = 0; c < 16; ++c) a += ws[OFF_UP + (size_t)c*(B*H*E) + id];
    ws[OFF_U + id] = a;
}

// ---------------- attn_pre[b][e] (16-lane-group GEMV) ----------------
__global__ __launch_bounds__(256) void k_attnpre(
    const float* __restrict__ ipw, const float* __restrict__ ipb,
    const float* __restrict__ bias_v, float* __restrict__ ws)
{
    int b  = blockIdx.x >> 6;
    int et = blockIdx.x & 63;
    int grp = threadIdx.x >> 4, l = threadIdx.x & 15;
    int e = et * 16 + grp;
    int h = e >> 6;
    const float* wvr = ipw + (size_t)(2*E + e) * E;   // Wv row e
    const float* ur  = ws + OFF_U + (size_t)(b*16 + h) * E;
    float acc = 0.f;
    #pragma unroll
    for (int ff = l * 4; ff < E; ff += 64) {
        float4 w4 = *(const float4*)(wvr + ff);
        float4 u4 = *(const float4*)(ur + ff);
        acc += w4.x*u4.x + w4.y*u4.y + w4.z*u4.z + w4.w*u4.w;
    }
    #pragma unroll
    for (int m = 8; m >= 1; m >>= 1) acc += __shfl_xor(acc, m, 64);
    if (l == 0) {
        float wS = ws[OFF_WT + ((size_t)(b*SRC + S) << 4) + h];
        ws[OFF_AP + b*E + e] = acc + ipb[2*E + e] * (1.0f - wS) + wS * bias_v[e];
    }
}

// ---------------- out projection (16-lane-group GEMV) ----------------
__global__ __launch_bounds__(256) void k_out(
    const float* __restrict__ ow, const float* __restrict__ ob,
    const float* __restrict__ ws, float* __restrict__ out)
{
    int b  = blockIdx.x >> 6;
    int et = blockIdx.x & 63;
    int grp = threadIdx.x >> 4, l = threadIdx.x & 15;
    int o = et * 16 + grp;
    const float* wr = ow + (size_t)o * E;
    const float* ap = ws + OFF_AP + b*E;
    float acc = 0.f;
    #pragma unroll
    for (int e = l * 4; e < E; e += 64) {
        float4 w4 = *(const float4*)(wr + e);
        float4 a4 = *(const float4*)(ap + e);
        acc += w4.x*a4.x + w4.y*a4.y + w4.z*a4.z + w4.w*a4.w;
    }
    #pragma unroll
    for (int m = 8; m >= 1; m >>= 1) acc += __shfl_xor(acc, m, 64);
    if (l == 0) out[b*E + o] = acc + ob[o];
}

extern "C" void kernel_launch(void* const* d_in, const int* in_sizes, int n_in,
                              void* d_out, int out_size, void* d_ws, size_t ws_size,
                              hipStream_t stream)
{
    const float* query   = (const float*)d_in[0];
    const float* key     = (const float*)d_in[1];
    const float* value   = (const float*)d_in[2];
    const float* context = (const float*)d_in[3];
    const float* ipw     = (const float*)d_in[4];
    const float* ipb     = (const float*)d_in[5];
    const float* cw      = (const float*)d_in[6];
    const float* cb      = (const float*)d_in[7];
    const float* ow      = (const float*)d_in[8];
    const float* ob      = (const float*)d_in[9];
    const float* bias_k  = (const float*)d_in[10];
    const float* bias_v  = (const float*)d_in[11];
    float* out = (float*)d_out;
    float* ws  = (float*)d_ws;

    hipLaunchKernelGGL(k_pre1,    dim3(1024), dim3(256),  0, stream, query, context, ipw, ipb, cw, cb, ws);
    hipLaunchKernelGGL(k_pre2,    dim3(1024), dim3(256),  0, stream, cw, ws);
    hipLaunchKernelGGL(k_pre3,    dim3(1024), dim3(256),  0, stream, cw, ws);
    hipLaunchKernelGGL(k_pre3b,   dim3(1),    dim3(256),  0, stream, bias_k, ws);
    hipLaunchKernelGGL(k_g,       dim3(512),  dim3(256),  0, stream, ipw, ws);
    hipLaunchKernelGGL(k_gsum,    dim3(1024), dim3(256),  0, stream, ws);
    hipLaunchKernelGGL(k_scores,  dim3(512),  dim3(512),  0, stream, key, ws);
    hipLaunchKernelGGL(k_softmax, dim3(256),  dim3(256),  0, stream, ws);
    hipLaunchKernelGGL(k_avg,     dim3(129),  dim3(256),  0, stream, ws, out);
    hipLaunchKernelGGL(k_u,       dim3(512),  dim3(256),  0, stream, value, ws);
    hipLaunchKernelGGL(k_ured,    dim3(1024), dim3(256),  0, stream, ws);
    hipLaunchKernelGGL(k_attnpre, dim3(1024), dim3(256),  0, stream, ipw, ipb, bias_v, ws);
    hipLaunchKernelGGL(k_out,     dim3(1024), dim3(256),  0, stream, ow, ob, ws, out);
}